// Round 6
// baseline (927.504 us; speedup 1.0000x reference)
//
#include <hip/hip_runtime.h>
#include <hip/hip_fp16.h>

// B=16 E=128 W=256 HID=64 HOR=12; row = b*128+e (2048 rows).
// Algebraic structure exploited:
//  (1) softmax row sums to 1 => adj_bin is one-hot-or-empty => GAT is exactly
//      h_temp[i] = gr[j*] (or mean_j gr[j] when fully masked); E_coup = E[j*] or 0.
//  (2) cnn telescopes: h(t)[p] = G[t+4p]; G[s] precomputable for s<253.
//  (3) gr(t) = grPre(t) (parallel, fp16) + <=3 sequential corrections (p=61,62,63).
// 3 launches. No cooperative launch (harness rejects it - measured twice).
// Round-6 fix: kscan register plan must respect the VGPR cap. launch_bounds
// (1024,4) -> 1 block/CU -> 128 VGPRs; w2 reloaded per step (L2-hit) instead
// of a 64-VGPR register array (round-5 spilled 26 MB to scratch -> 385 us).

struct Params {
  const float *__restrict__ x, *__restrict__ noise, *__restrict__ aw, *__restrict__ ab,
              *__restrict__ pe_w1, *__restrict__ pe_b1, *__restrict__ bn_g, *__restrict__ bn_b,
              *__restrict__ bn_m, *__restrict__ bn_v, *__restrict__ pe_w2, *__restrict__ pe_b2,
              *__restrict__ w1, *__restrict__ b1, *__restrict__ w2, *__restrict__ b2,
              *__restrict__ w3, *__restrict__ b3, *__restrict__ wl, *__restrict__ bl,
              *__restrict__ wr, *__restrict__ br, *__restrict__ attn, *__restrict__ out_w,
              *__restrict__ out_b, *__restrict__ ce_w, *__restrict__ ce_b, *__restrict__ cd_w,
              *__restrict__ cd_b, *__restrict__ q_w, *__restrict__ q_b, *__restrict__ k_w,
              *__restrict__ k_b;
  float* ws;
  float* out;
};

__device__ __forceinline__ float fast_tanh(float x) {
  float t = exp2f(fminf(2.8853900818f * x, 126.0f));   // exp(2x)
  return 1.0f - 2.0f * __builtin_amdgcn_rcpf(t + 1.0f);
}
__device__ __forceinline__ float fast_sigmoid(float x) {
  float t = exp2f(fminf(-1.44269504f * x, 126.0f));
  return __builtin_amdgcn_rcpf(1.0f + t);
}
__device__ __forceinline__ float wsum(float v) {
  #pragma unroll
  for (int m = 1; m < 64; m <<= 1) v += __shfl_xor(v, m, 64);
  return v;
}
__device__ __forceinline__ float wmax(float v) {
  #pragma unroll
  for (int m = 1; m < 64; m <<= 1) v = fmaxf(v, __shfl_xor(v, m, 64));
  return v;
}

// workspace layout (float offsets), total 1450016 floats ~= 5.7 MB
#define OFF_GRP  0        // fp16 grPre: 12 x 2048 x 64 halves = 786432 floats
#define OFF_G    786432   // G: 2048 x 256 (s<253 valid)
#define OFF_QV   1310720  // 2048 x 32
#define OFF_KV   1376256  // 2048 x 32
#define OFF_XT   1441792  // xtail: 2048 x 3 (window cols 253,254,255)
#define OFF_JS   1447936  // jstar: 2048 ints
#define OFF_MS   1449984  // mean[16], std[16]

// ---------- kA: fused norm+conv5+bn+conv1x1+affine -> xrow (LDS) -> G, q/k, xtail ----------
__global__ __launch_bounds__(256, 4)
void kA(Params P) {
  __shared__ float xrow[256];
  __shared__ float red[8];
  __shared__ float pp[256];
  const int tid = threadIdx.x, blk = blockIdx.x;
  const int b = blk >> 7, e = blk & 127, w = tid;
  const int lane = tid & 63, wv = tid >> 6;
  float* ws = P.ws;

  float v = P.x[b * 256 + w];
  float s = wsum(v), s2 = wsum(v * v);
  if (lane == 0) { red[wv] = s; red[4 + wv] = s2; }
  __syncthreads();
  float st  = red[0] + red[1] + red[2] + red[3];
  float st2 = red[4] + red[5] + red[6] + red[7];
  float mean = st * (1.f / 256.f);
  float var  = st2 * (1.f / 256.f) - mean * mean;
  float sd   = sqrtf(var);
  if (e == 0 && tid == 0) { ws[OFF_MS + b] = mean; ws[OFF_MS + 16 + b] = sd; }
  float rstd = 1.f / sd;

  float xv[5];
  #pragma unroll
  for (int k = 0; k < 5; k++) {
    int u = w - 2 + k;
    xv[k] = (u >= 0 && u < 256) ? (P.x[b * 256 + u] - mean) * rstd : 0.f;
  }
  float acc = P.pe_b2[e];
  #pragma unroll 4
  for (int c = 0; c < 32; c++) {
    float a = P.pe_b1[c];
    #pragma unroll
    for (int k = 0; k < 5; k++) a += P.pe_w1[c * 5 + k] * xv[k];
    a = fmaxf(a, 0.f);
    float sc = P.bn_g[c] / sqrtf(P.bn_v[c] + 1e-5f);
    float h0 = (a - P.bn_m[c]) * sc + P.bn_b[c];
    acc += P.pe_w2[e * 32 + c] * h0;
  }
  acc = acc * P.aw[e] + P.ab[e];
  xrow[w] = acc;
  __syncthreads();

  if (tid < 3) ws[OFF_XT + blk * 3 + tid] = xrow[253 + tid];

  if (tid < 253) {
    const int s0 = tid;
    const float* w1p = P.w1 + e * 128;
    const float* w2p = P.w2 + e * 512;
    const float* w3p = P.w3 + e * 64;
    const float* b1p = P.b1 + e * 64;
    const float* b2p = P.b2 + e * 64;
    float X0 = xrow[s0], X1 = xrow[s0 + 1], X2 = xrow[s0 + 2], X3 = xrow[s0 + 3];
    float a3 = 0.f;
    #pragma unroll 1
    for (int g2 = 0; g2 < 16; g2++) {
      float h1v[8];
      #pragma unroll
      for (int ic = 0; ic < 4; ic++) {
        int ch = g2 * 4 + ic;
        float ww0 = w1p[ch * 2], ww1 = w1p[ch * 2 + 1], bb = b1p[ch];
        h1v[ic * 2 + 0] = fast_tanh(bb + ww0 * X0 + ww1 * X1);
        h1v[ic * 2 + 1] = fast_tanh(bb + ww0 * X2 + ww1 * X3);
      }
      #pragma unroll
      for (int oc = 0; oc < 4; oc++) {
        int ch = g2 * 4 + oc;
        const float* wq = w2p + ch * 8;
        float a2 = b2p[ch];
        #pragma unroll
        for (int u = 0; u < 8; u++) a2 += wq[u] * h1v[u];
        a3 += w3p[ch] * fast_tanh(a2);
      }
    }
    ws[OFF_G + blk * 256 + tid] = fast_tanh(P.b3[e] + a3);
  }

  {
    const int u = tid >> 2, c = tid & 3;
    const int h = u & 31;
    const float* wm = (u < 32) ? P.q_w : P.k_w;
    const float* wp = wm + h * 256 + c * 64;
    const float* xp = xrow + c * 64;
    float a = 0.f;
    #pragma unroll 4
    for (int i = 0; i < 64; i += 4) {
      float4 xx = *(const float4*)(xp + i);
      float4 wq = *(const float4*)(wp + i);
      a += xx.x * wq.x + xx.y * wq.y + xx.z * wq.z + xx.w * wq.w;
    }
    pp[tid] = a;
  }
  __syncthreads();
  if (tid < 64) {
    float r = pp[tid * 4] + pp[tid * 4 + 1] + pp[tid * 4 + 2] + pp[tid * 4 + 3];
    if (tid < 32) ws[OFF_QV + blk * 32 + tid] = r + P.q_b[tid];
    else          ws[OFF_KV + blk * 32 + tid - 32] = r + P.k_b[tid - 32];
  }
}

// ---------- kmid: blocks<512: adjacency softmax + jstar; blocks>=512: grPre (fp16) ----------
__global__ __launch_bounds__(256)
void kmid(Params P) {
  __shared__ float pool[272];
  const int tid = threadIdx.x, blk = blockIdx.x;
  float* ws = P.ws;

  if (blk < 512) {
    const int lane = tid & 63, wv = tid >> 6;
    const int row = blk * 4 + wv;
    const int b = row >> 7;
    float* hb = pool + wv * 64;
    if (lane < 32) hb[lane] = ws[OFF_QV + row * 32 + lane];
    __syncthreads();
    float ev0, ev1;
    #pragma unroll
    for (int half = 0; half < 2; half++) {
      int j = lane + half * 64;
      const float* kr = ws + OFF_KV + (b * 128 + j) * 32;
      float a = 0.f;
      #pragma unroll
      for (int h = 0; h < 32; h += 4) {
        float4 kk = *(const float4*)(kr + h);
        float4 qq = *(const float4*)(hb + h);
        a += qq.x * kk.x + qq.y * kk.y + qq.z * kk.z + qq.w * kk.w;
      }
      if (half == 0) ev0 = a; else ev1 = a;
    }
    float m   = wmax(fmaxf(ev0, ev1));
    float p0  = __expf(ev0 - m), p1 = __expf(ev1 - m);
    float inv = 1.f / wsum(p0 + p1);
    float a0 = p0 * inv, a1 = p1 * inv;
    P.out[38912 + row * 128 + lane]      = a0;
    P.out[38912 + row * 128 + lane + 64] = a1;
    unsigned long long m0 = __ballot(a0 > 0.5f);
    unsigned long long m1 = __ballot(a1 > 0.5f);
    if (lane == 0) {
      int js = m0 ? (int)__builtin_ctzll(m0) : (m1 ? 64 + (int)__builtin_ctzll(m1) : -1);
      ((int*)(ws + OFF_JS))[row] = js;
    }
  } else {
    const int row = blk - 512;
    float* GS = pool;
    if (tid < 253) GS[tid] = ws[OFF_G + row * 256 + tid];
    __syncthreads();
    __half* gph = (__half*)(ws + OFF_GRP);
    const int o = tid & 63, tg = tid >> 6;
    #pragma unroll
    for (int k = 0; k < 3; k++) {
      int t = tg * 3 + k;
      int pmax = (256 - t) >> 2;
      const float* wro = P.wr + o * 64;
      float a = P.br[o];
      #pragma unroll 4
      for (int p = 0; p < pmax; p++) a += GS[t + 4 * p] * wro[p];
      gph[((size_t)t * 2048 + row) * 64 + o] = __float2half(a);
    }
  }
}

// ---------- kscan: 16 blocks (block=b) x 1024 threads; single fused phase per step ----------
// launch_bounds(1024,4): 16 waves = 1 block/CU -> VGPR cap 128. Per-row register
// arrays kept below that cap; w2 reloaded per step (same addresses, L2-hit).
__global__ __launch_bounds__(1024, 4)
void kscan(Params P) {
  __shared__ float GlateS[12 * 128];    // G[row][253+t']
  __shared__ float QS[2 * 3 * 128];     // double-buffered Q
  __shared__ float meanPreS[12 * 64];
  __shared__ int   jstarS[128];
  __shared__ float GsumS[12];

  const int tid = threadIdx.x, lane = tid & 63, wv = tid >> 6;
  const int b = blockIdx.x;
  float* ws = P.ws;
  const __half* gph = (const __half*)(ws + OFF_GRP);
  const float* Gg = ws + OFF_G;

  // ---- setup ----
  if (tid < 12) GsumS[tid] = 0.f;
  if (tid < 128) {
    jstarS[tid] = ((const int*)(ws + OFF_JS))[b * 128 + tid];
    QS[tid] = 1.f; QS[128 + tid] = 0.f; QS[256 + tid] = 0.f;
  }
  if (tid < 768) {   // meanPre[t][o] = mean_j grPre[t][j][o]
    int t = tid >> 6, o = tid & 63;
    const __half* gp = gph + ((size_t)t * 2048 + b * 128) * 64 + o;
    float sm = 0.f;
    #pragma unroll 8
    for (int j = 0; j < 128; j++) sm += __half2float(gp[j * 64]);
    meanPreS[tid] = sm * (1.f / 128.f);
  }

  // ---- lane-constant and per-row register preloads (~72 VGPRs of arrays) ----
  float cew0 = P.ce_w[lane * 3], cew1 = P.ce_w[lane * 3 + 1], cew2 = P.ce_w[lane * 3 + 2];
  float cebv = P.ce_b[lane];
  float cdw0 = P.cd_w[lane], cdw1 = P.cd_w[64 + lane], cdw2 = P.cd_w[128 + lane], cdw3 = P.cd_w[192 + lane];
  float cdb0 = P.cd_b[0], cdb1 = P.cd_b[1], cdb2 = P.cd_b[2], cdb3 = P.cd_b[3];
  float wr61 = P.wr[lane * 64 + 61], wr62 = P.wr[lane * 64 + 62], wr63 = P.wr[lane * 64 + 63];

  float X0r[8], X1r[8], X2r[8], outwR[8];
  float w1xR[8], w1yR[8], b1R[8], b2R[8], w3R[8];
  #pragma unroll
  for (int r = 0; r < 8; r++) {
    const int rowL = wv * 8 + r, e = rowL, row = b * 128 + rowL;
    X0r[r] = ws[OFF_XT + row * 3 + 0];
    X1r[r] = ws[OFF_XT + row * 3 + 1];
    X2r[r] = ws[OFF_XT + row * 3 + 2];
    outwR[r] = P.out_w[e * 64 + lane];
    float2 w1v = ((const float2*)(P.w1 + e * 128))[lane];
    w1xR[r] = w1v.x; w1yR[r] = w1v.y;
    b1R[r] = P.b1[e * 64 + lane]; b2R[r] = P.b2[e * 64 + lane];
    w3R[r] = P.w3[e * 64 + lane];
  }
  __syncthreads();

  const float meanb = ws[OFF_MS + b], stdb = ws[OFF_MS + 16 + b];

  for (int t = 0; t < 12; t++) {
    const int par = (t & 1) * 384, parn = ((t + 1) & 1) * 384;

    // batched loads for all 8 rows (hide L2 latency)
    float gv[8], hov[8];
    #pragma unroll
    for (int r = 0; r < 8; r++) {
      const int rowL = wv * 8 + r;
      const int jj = jstarS[rowL];
      gv[r] = (jj >= 0)
            ? __half2float(gph[((size_t)t * 2048 + b * 128 + jj) * 64 + lane])
            : meanPreS[t * 64 + lane];
      int s0 = t + 4 * lane;
      hov[r] = (s0 < 253) ? Gg[((size_t)b * 128 + rowL) * 256 + s0]
                          : GlateS[(s0 - 253) * 128 + rowL];
    }

    float gsum_loc = 0.f;
    #pragma unroll
    for (int r = 0; r < 8; r++) {
      const int rowL = wv * 8 + r, e = rowL, row = b * 128 + rowL;
      const int jj = jstarS[rowL];

      // issue w2 loads early; ~40 VALU ops before first use hide the latency
      const float* w2p = P.w2 + e * 512 + lane * 8;
      float4 wlo = *(const float4*)(w2p);
      float4 whi = *(const float4*)(w2p + 4);
      float nz = P.noise[t * 2048 + row];    // wave-uniform scalar load

      // gr[j*](t) with sequential corrections (p = 63, 62, 61)
      float ht = gv[r];
      if (t >= 1) {
        float g = (jj >= 0) ? GlateS[(t - 1) * 128 + jj] : GsumS[t - 1] * (1.f / 128.f);
        ht += g * wr63;
      }
      if (t >= 5) {
        float g = (jj >= 0) ? GlateS[(t - 5) * 128 + jj] : GsumS[t - 5] * (1.f / 128.f);
        ht += g * wr62;
      }
      if (t >= 9) {
        float g = (jj >= 0) ? GlateS[(t - 9) * 128 + jj] : GsumS[t - 9] * (1.f / 128.f);
        ht += g * wr61;
      }

      float q0 = QS[par + rowL], q1 = QS[par + 128 + rowL], q2 = QS[par + 256 + rowL];
      float hc = fast_tanh(cebv + q0 * cew0 + q1 * cew1 + q2 * cew2);
      float hf = hov[r] + fast_tanh(ht) + hc;

      // 5 simultaneous wave reductions (independent butterfly chains)
      float vxp = hf * outwR[r], v0 = hf * cdw0, v1 = hf * cdw1, v2 = hf * cdw2, v3 = hf * cdw3;
      #pragma unroll
      for (int m = 1; m < 64; m <<= 1) {
        vxp += __shfl_xor(vxp, m, 64);
        v0 += __shfl_xor(v0, m, 64);
        v1 += __shfl_xor(v1, m, 64);
        v2 += __shfl_xor(v2, m, 64);
        v3 += __shfl_xor(v3, m, 64);
      }
      float xp = vxp + P.out_b[e];
      float al = fast_sigmoid(v0 + cdb0);
      float be = fast_sigmoid(v1 + cdb1);
      float ga = fast_sigmoid(v2 + cdb2);
      float et = fast_sigmoid(v3 + cdb3);

      float Ec = (jj >= 0) ? QS[par + 128 + jj] : 0.f;
      float Hn = q0 - al * q0;
      float En = q1 + be * q0 - ga * q1 + 0.1f * Ec;
      float Vn = q2 + et * q1 + nz * 0.01f;
      if (lane == 0) {
        QS[parn + rowL] = Hn; QS[parn + 128 + rowL] = En; QS[parn + 256 + rowL] = Vn;
        P.out[row * 12 + t] = (xp - P.ab[e]) / P.aw[e] * stdb + meanb;
        if (t == 11) {
          P.out[24576 + row * 3] = Hn; P.out[24576 + row * 3 + 1] = En; P.out[24576 + row * 3 + 2] = Vn;
          P.out[30720 + row * 4] = al; P.out[30720 + row * 4 + 1] = be;
          P.out[30720 + row * 4 + 2] = ga; P.out[30720 + row * 4 + 3] = et;
        }
      }

      // incremental CNN column (lane = channel)
      if (t < 11) {
        float h1a = fast_tanh(b1R[r] + w1xR[r] * X0r[r] + w1yR[r] * X1r[r]);
        float h1c = fast_tanh(b1R[r] + w1xR[r] * X2r[r] + w1yR[r] * xp);
        int src = (lane >> 2) * 4;
        float a2 = b2R[r];
        a2 += wlo.x * __shfl(h1a, src + 0, 64) + wlo.y * __shfl(h1c, src + 0, 64);
        a2 += wlo.z * __shfl(h1a, src + 1, 64) + wlo.w * __shfl(h1c, src + 1, 64);
        a2 += whi.x * __shfl(h1a, src + 2, 64) + whi.y * __shfl(h1c, src + 2, 64);
        a2 += whi.z * __shfl(h1a, src + 3, 64) + whi.w * __shfl(h1c, src + 3, 64);
        float h2 = fast_tanh(a2);
        float g3 = wsum(w3R[r] * h2);
        float Gn = fast_tanh(P.b3[e] + g3);
        if (lane == 0) GlateS[t * 128 + rowL] = Gn;
        gsum_loc += Gn;
        X0r[r] = X1r[r]; X1r[r] = X2r[r]; X2r[r] = xp;
      }
    }
    if (t < 11 && lane == 0) atomicAdd(&GsumS[t], gsum_loc);
    __syncthreads();
  }
}

extern "C" void kernel_launch(void* const* d_in, const int* in_sizes, int n_in,
                              void* d_out, int out_size, void* d_ws, size_t ws_size,
                              hipStream_t stream) {
  Params p;
  p.x     = (const float*)d_in[0];  p.noise = (const float*)d_in[1];
  p.aw    = (const float*)d_in[2];  p.ab    = (const float*)d_in[3];
  p.pe_w1 = (const float*)d_in[4];  p.pe_b1 = (const float*)d_in[5];
  p.bn_g  = (const float*)d_in[6];  p.bn_b  = (const float*)d_in[7];
  p.bn_m  = (const float*)d_in[8];  p.bn_v  = (const float*)d_in[9];
  p.pe_w2 = (const float*)d_in[10]; p.pe_b2 = (const float*)d_in[11];
  p.w1    = (const float*)d_in[12]; p.b1    = (const float*)d_in[13];
  p.w2    = (const float*)d_in[14]; p.b2    = (const float*)d_in[15];
  p.w3    = (const float*)d_in[16]; p.b3    = (const float*)d_in[17];
  p.wl    = (const float*)d_in[18]; p.bl    = (const float*)d_in[19];
  p.wr    = (const float*)d_in[20]; p.br    = (const float*)d_in[21];
  p.attn  = (const float*)d_in[22]; p.out_w = (const float*)d_in[23];
  p.out_b = (const float*)d_in[24]; p.ce_w  = (const float*)d_in[25];
  p.ce_b  = (const float*)d_in[26]; p.cd_w  = (const float*)d_in[27];
  p.cd_b  = (const float*)d_in[28]; p.q_w   = (const float*)d_in[29];
  p.q_b   = (const float*)d_in[30]; p.k_w   = (const float*)d_in[31];
  p.k_b   = (const float*)d_in[32];
  p.ws  = (float*)d_ws;
  p.out = (float*)d_out;

  kA   <<<dim3(2048), dim3(256),  0, stream>>>(p);
  kmid <<<dim3(2560), dim3(256),  0, stream>>>(p);
  kscan<<<dim3(16),   dim3(1024), 0, stream>>>(p);
}

// Round 7
// 595.704 us; speedup vs baseline: 1.5570x; 1.5570x over previous
//
#include <hip/hip_runtime.h>
#include <hip/hip_fp16.h>

// B=16 E=128 W=256 HID=64 HOR=12; row = b*128+e (2048 rows).
// Algebraic structure exploited:
//  (1) softmax row sums to 1 => adj_bin is one-hot-or-empty => GAT is exactly
//      h_temp[i] = gr[j*] (or mean_j gr[j] when fully masked); E_coup = E[j*] or 0.
//  (2) cnn telescopes: h(t)[p] = G[t+4p]; G[s] precomputable for s<253.
//  (3) gr(t) = grPre(t) (parallel, fp16) + <=3 sequential corrections (p=61,62,63).
// 2 launches: kA (everything row-parallel incl. grPre), kscan (adjacency + scan).
// No cooperative launch (harness rejects it - measured twice).
// Round-7 lesson: 1024-thread blocks get a hard 64-VGPR allocation from this
// compiler (rounds 5+6 spilled 15-69 MB to scratch). kscan loop body therefore
// holds NO register arrays: per-row state lives in LDS (broadcast reads are
// free), per-row weights are global loads (L1-hit after t=0), unroll 1.

struct Params {
  const float *__restrict__ x, *__restrict__ noise, *__restrict__ aw, *__restrict__ ab,
              *__restrict__ pe_w1, *__restrict__ pe_b1, *__restrict__ bn_g, *__restrict__ bn_b,
              *__restrict__ bn_m, *__restrict__ bn_v, *__restrict__ pe_w2, *__restrict__ pe_b2,
              *__restrict__ w1, *__restrict__ b1, *__restrict__ w2, *__restrict__ b2,
              *__restrict__ w3, *__restrict__ b3, *__restrict__ wl, *__restrict__ bl,
              *__restrict__ wr, *__restrict__ br, *__restrict__ attn, *__restrict__ out_w,
              *__restrict__ out_b, *__restrict__ ce_w, *__restrict__ ce_b, *__restrict__ cd_w,
              *__restrict__ cd_b, *__restrict__ q_w, *__restrict__ q_b, *__restrict__ k_w,
              *__restrict__ k_b;
  float* ws;
  float* out;
};

__device__ __forceinline__ float fast_tanh(float x) {
  float t = exp2f(fminf(2.8853900818f * x, 126.0f));   // exp(2x)
  return 1.0f - 2.0f * __builtin_amdgcn_rcpf(t + 1.0f);
}
__device__ __forceinline__ float fast_sigmoid(float x) {
  float t = exp2f(fminf(-1.44269504f * x, 126.0f));
  return __builtin_amdgcn_rcpf(1.0f + t);
}
__device__ __forceinline__ float wsum(float v) {
  #pragma unroll
  for (int m = 1; m < 64; m <<= 1) v += __shfl_xor(v, m, 64);
  return v;
}
__device__ __forceinline__ float wmax(float v) {
  #pragma unroll
  for (int m = 1; m < 64; m <<= 1) v = fmaxf(v, __shfl_xor(v, m, 64));
  return v;
}

// workspace layout (float offsets), total 1447968 floats ~= 5.8 MB
#define OFF_GRP  0        // fp16 grPre: 12 x 2048 x 64 halves = 786432 floats
#define OFF_G    786432   // G: 2048 x 256 (s<253 valid)
#define OFF_QV   1310720  // 2048 x 32
#define OFF_KV   1376256  // 2048 x 32
#define OFF_XT   1441792  // xtail: 2048 x 3 (window cols 253,254,255)
#define OFF_MS   1447936  // mean[16], std[16]

// ---------- kA: norm+conv5+bn+conv1x1+affine -> xrow -> G, grPre, q/k, xtail ----------
// grid 2048 (block=(b,e)), 256 threads, 8 blocks/CU.
__global__ __launch_bounds__(256, 8)
void kA(Params P) {
  __shared__ float xrow[256];
  __shared__ float GS[256];
  __shared__ float red[8];
  __shared__ float pp[256];
  const int tid = threadIdx.x, blk = blockIdx.x;
  const int b = blk >> 7, e = blk & 127, w = tid;
  const int lane = tid & 63, wv = tid >> 6;
  float* ws = P.ws;

  // per-b mean/std (block-redundant, consistent across e)
  float v = P.x[b * 256 + w];
  float s = wsum(v), s2 = wsum(v * v);
  if (lane == 0) { red[wv] = s; red[4 + wv] = s2; }
  __syncthreads();
  float st  = red[0] + red[1] + red[2] + red[3];
  float st2 = red[4] + red[5] + red[6] + red[7];
  float mean = st * (1.f / 256.f);
  float var  = st2 * (1.f / 256.f) - mean * mean;
  float sd   = sqrtf(var);
  if (e == 0 && tid == 0) { ws[OFF_MS + b] = mean; ws[OFF_MS + 16 + b] = sd; }
  float rstd = 1.f / sd;

  // xf(w) = affine(conv1x1(bn(relu(conv5(xn)))))
  float xv[5];
  #pragma unroll
  for (int k = 0; k < 5; k++) {
    int u = w - 2 + k;
    xv[k] = (u >= 0 && u < 256) ? (P.x[b * 256 + u] - mean) * rstd : 0.f;
  }
  float acc = P.pe_b2[e];
  #pragma unroll 4
  for (int c = 0; c < 32; c++) {
    float a = P.pe_b1[c];
    #pragma unroll
    for (int k = 0; k < 5; k++) a += P.pe_w1[c * 5 + k] * xv[k];
    a = fmaxf(a, 0.f);
    float sc = P.bn_g[c] / sqrtf(P.bn_v[c] + 1e-5f);
    float h0 = (a - P.bn_m[c]) * sc + P.bn_b[c];
    acc += P.pe_w2[e * 32 + c] * h0;
  }
  acc = acc * P.aw[e] + P.ab[e];
  xrow[w] = acc;
  __syncthreads();

  if (tid < 3) ws[OFF_XT + blk * 3 + tid] = xrow[253 + tid];

  // q/k partials (uses xrow only)
  {
    const int u = tid >> 2, c = tid & 3;
    const int h = u & 31;
    const float* wm = (u < 32) ? P.q_w : P.k_w;
    const float* wp = wm + h * 256 + c * 64;
    const float* xp = xrow + c * 64;
    float a = 0.f;
    #pragma unroll 4
    for (int i = 0; i < 64; i += 4) {
      float4 xx = *(const float4*)(xp + i);
      float4 wq = *(const float4*)(wp + i);
      a += xx.x * wq.x + xx.y * wq.y + xx.z * wq.z + xx.w * wq.w;
    }
    pp[tid] = a;
  }

  // telescoped CNN: thread = s
  if (tid < 253) {
    const int s0 = tid;
    const float* w1p = P.w1 + e * 128;
    const float* w2p = P.w2 + e * 512;
    const float* w3p = P.w3 + e * 64;
    const float* b1p = P.b1 + e * 64;
    const float* b2p = P.b2 + e * 64;
    float X0 = xrow[s0], X1 = xrow[s0 + 1], X2 = xrow[s0 + 2], X3 = xrow[s0 + 3];
    float a3 = 0.f;
    #pragma unroll 1
    for (int g2 = 0; g2 < 16; g2++) {
      float h1v[8];
      #pragma unroll
      for (int ic = 0; ic < 4; ic++) {
        int ch = g2 * 4 + ic;
        float ww0 = w1p[ch * 2], ww1 = w1p[ch * 2 + 1], bb = b1p[ch];
        h1v[ic * 2 + 0] = fast_tanh(bb + ww0 * X0 + ww1 * X1);
        h1v[ic * 2 + 1] = fast_tanh(bb + ww0 * X2 + ww1 * X3);
      }
      #pragma unroll
      for (int oc = 0; oc < 4; oc++) {
        int ch = g2 * 4 + oc;
        const float* wq = w2p + ch * 8;
        float a2 = b2p[ch];
        #pragma unroll
        for (int u = 0; u < 8; u++) a2 += wq[u] * h1v[u];
        a3 += w3p[ch] * fast_tanh(a2);
      }
    }
    float Gv = fast_tanh(P.b3[e] + a3);
    GS[tid] = Gv;
    ws[OFF_G + blk * 256 + tid] = Gv;
  }
  __syncthreads();

  // q/k finalize
  if (tid < 64) {
    float r = pp[tid * 4] + pp[tid * 4 + 1] + pp[tid * 4 + 2] + pp[tid * 4 + 3];
    if (tid < 32) ws[OFF_QV + blk * 32 + tid] = r + P.q_b[tid];
    else          ws[OFF_KV + blk * 32 + tid - 32] = r + P.k_b[tid - 32];
  }

  // grPre[t][row][o] = br[o] + sum_{p: t+4p<253} GS[t+4p] * wr[o][p]  (fp16)
  {
    __half* gph = (__half*)(ws + OFF_GRP);
    const int o = tid & 63, tg = tid >> 6;
    #pragma unroll
    for (int k = 0; k < 3; k++) {
      int t = tg * 3 + k;
      int pmax = (256 - t) >> 2;
      const float* wro = P.wr + o * 64;
      float a = P.br[o];
      #pragma unroll 4
      for (int p = 0; p < pmax; p++) a += GS[t + 4 * p] * wro[p];
      gph[((size_t)t * 2048 + blk) * 64 + o] = __float2half(a);
    }
  }
}

// ---------- kscan: 16 blocks (block=b) x 1024 threads ----------
// Adjacency + jstar in setup (LDS-only), then 12 scan steps, one barrier each.
// NO register arrays in the loop: per-row state in LDS, weights via L1.
__global__ __launch_bounds__(1024)
void kscan(Params P) {
  __shared__ float QS[2 * 3 * 128];     // double-buffered Q
  __shared__ float GlateS[11 * 128];    // G[row][253+t'], t'=0..10
  __shared__ float meanPreS[12 * 64];
  __shared__ float xhS[128 * 4];        // X0,X1,X2 per row
  __shared__ float qS[16 * 32];         // per-wave q staging
  __shared__ int   jstarS[128];
  __shared__ float GsumS[12];

  const int tid = threadIdx.x, lane = tid & 63, wv = tid >> 6;
  const int b = blockIdx.x;
  float* ws = P.ws;
  const __half* gph = (const __half*)(ws + OFF_GRP);
  const float* Gg = ws + OFF_G;

  // ---- setup: scalars ----
  if (tid < 12) GsumS[tid] = 0.f;
  if (tid < 128) {
    QS[tid] = 1.f; QS[128 + tid] = 0.f; QS[256 + tid] = 0.f;
    xhS[tid * 4 + 0] = ws[OFF_XT + (b * 128 + tid) * 3 + 0];
    xhS[tid * 4 + 1] = ws[OFF_XT + (b * 128 + tid) * 3 + 1];
    xhS[tid * 4 + 2] = ws[OFF_XT + (b * 128 + tid) * 3 + 2];
  }

  // ---- setup: adjacency softmax + jstar (one wave per row, 8 rows/wave) ----
  #pragma unroll 1
  for (int r = 0; r < 8; r++) {
    const int rowL = wv * 8 + r, row = b * 128 + rowL;
    if (lane < 32) qS[wv * 32 + lane] = ws[OFF_QV + row * 32 + lane];
    // same-wave LDS RAW: compiler inserts lgkmcnt wait; no barrier needed
    float ev0, ev1;
    #pragma unroll
    for (int half = 0; half < 2; half++) {
      int j = lane + half * 64;
      const float* kr = ws + OFF_KV + (b * 128 + j) * 32;
      float a = 0.f;
      #pragma unroll
      for (int h = 0; h < 32; h += 4) {
        float4 kk = *(const float4*)(kr + h);
        a += qS[wv * 32 + h] * kk.x + qS[wv * 32 + h + 1] * kk.y
           + qS[wv * 32 + h + 2] * kk.z + qS[wv * 32 + h + 3] * kk.w;
      }
      if (half == 0) ev0 = a; else ev1 = a;
    }
    float m   = wmax(fmaxf(ev0, ev1));
    float p0  = __expf(ev0 - m), p1 = __expf(ev1 - m);
    float inv = 1.f / wsum(p0 + p1);
    float a0 = p0 * inv, a1 = p1 * inv;
    P.out[38912 + row * 128 + lane]      = a0;
    P.out[38912 + row * 128 + lane + 64] = a1;
    unsigned long long m0 = __ballot(a0 > 0.5f);
    unsigned long long m1 = __ballot(a1 > 0.5f);
    if (lane == 0) {
      jstarS[rowL] = m0 ? (int)__builtin_ctzll(m0)
                        : (m1 ? 64 + (int)__builtin_ctzll(m1) : -1);
    }
  }

  // ---- setup: meanPre[t][o] = mean_j grPre[t][j][o] ----
  if (tid < 768) {
    int t = tid >> 6, o = tid & 63;
    const __half* gp = gph + ((size_t)t * 2048 + b * 128) * 64 + o;
    float sm = 0.f;
    #pragma unroll 8
    for (int j = 0; j < 128; j++) sm += __half2float(gp[j * 64]);
    meanPreS[tid] = sm * (1.f / 128.f);
  }
  __syncthreads();

  // ---- lane constants (14 VGPRs) ----
  float cew0 = P.ce_w[lane * 3], cew1 = P.ce_w[lane * 3 + 1], cew2 = P.ce_w[lane * 3 + 2];
  float cebv = P.ce_b[lane];
  float cdw0 = P.cd_w[lane], cdw1 = P.cd_w[64 + lane], cdw2 = P.cd_w[128 + lane], cdw3 = P.cd_w[192 + lane];
  float cdb0 = P.cd_b[0], cdb1 = P.cd_b[1], cdb2 = P.cd_b[2], cdb3 = P.cd_b[3];
  float wr61 = P.wr[lane * 64 + 61], wr62 = P.wr[lane * 64 + 62], wr63 = P.wr[lane * 64 + 63];
  const float meanb = ws[OFF_MS + b], stdb = ws[OFF_MS + 16 + b];

  #pragma unroll 1
  for (int t = 0; t < 12; t++) {
    const int par = (t & 1) * 384, parn = ((t + 1) & 1) * 384;

    float gsum_loc = 0.f;
    #pragma unroll 1
    for (int r = 0; r < 8; r++) {
      const int rowL = wv * 8 + r, e = rowL, row = b * 128 + rowL;
      const int jj = jstarS[rowL];

      // loads (all issued up front; weights L1-hit after t=0)
      float gv = (jj >= 0)
               ? __half2float(gph[((size_t)t * 2048 + b * 128 + jj) * 64 + lane])
               : meanPreS[t * 64 + lane];
      int s0 = t + 4 * lane;
      float hov = (s0 < 253) ? Gg[(size_t)row * 256 + s0]
                             : GlateS[(s0 - 253) * 128 + rowL];
      float outw = P.out_w[e * 64 + lane];
      const float* w2p = P.w2 + e * 512 + lane * 8;
      float4 wlo = *(const float4*)(w2p);
      float4 whi = *(const float4*)(w2p + 4);
      float2 w1v = ((const float2*)(P.w1 + e * 128))[lane];
      float b1v = P.b1[e * 64 + lane], b2v = P.b2[e * 64 + lane], w3v = P.w3[e * 64 + lane];
      float nz = P.noise[t * 2048 + row];
      float X0 = xhS[rowL * 4 + 0], X1 = xhS[rowL * 4 + 1], X2 = xhS[rowL * 4 + 2];
      float q0 = QS[par + rowL], q1 = QS[par + 128 + rowL], q2 = QS[par + 256 + rowL];

      // gr[j*](t): grPre + sequential corrections (p = 63, 62, 61)
      float ht = gv;
      if (t >= 1) {
        float g = (jj >= 0) ? GlateS[(t - 1) * 128 + jj] : GsumS[t - 1] * (1.f / 128.f);
        ht += g * wr63;
      }
      if (t >= 5) {
        float g = (jj >= 0) ? GlateS[(t - 5) * 128 + jj] : GsumS[t - 5] * (1.f / 128.f);
        ht += g * wr62;
      }
      if (t >= 9) {
        float g = (jj >= 0) ? GlateS[(t - 9) * 128 + jj] : GsumS[t - 9] * (1.f / 128.f);
        ht += g * wr61;
      }

      float hc = fast_tanh(cebv + q0 * cew0 + q1 * cew1 + q2 * cew2);
      float hf = hov + fast_tanh(ht) + hc;

      // 5 simultaneous wave reductions
      float vxp = hf * outw, v0 = hf * cdw0, v1 = hf * cdw1, v2 = hf * cdw2, v3 = hf * cdw3;
      #pragma unroll
      for (int m = 1; m < 64; m <<= 1) {
        vxp += __shfl_xor(vxp, m, 64);
        v0 += __shfl_xor(v0, m, 64);
        v1 += __shfl_xor(v1, m, 64);
        v2 += __shfl_xor(v2, m, 64);
        v3 += __shfl_xor(v3, m, 64);
      }
      float xp = vxp + P.out_b[e];
      float al = fast_sigmoid(v0 + cdb0);
      float be = fast_sigmoid(v1 + cdb1);
      float ga = fast_sigmoid(v2 + cdb2);
      float et = fast_sigmoid(v3 + cdb3);

      float Ec = (jj >= 0) ? QS[par + 128 + jj] : 0.f;
      float Hn = q0 - al * q0;
      float En = q1 + be * q0 - ga * q1 + 0.1f * Ec;
      float Vn = q2 + et * q1 + nz * 0.01f;
      if (lane == 0) {
        QS[parn + rowL] = Hn; QS[parn + 128 + rowL] = En; QS[parn + 256 + rowL] = Vn;
        P.out[row * 12 + t] = (xp - P.ab[e]) / P.aw[e] * stdb + meanb;
        if (t == 11) {
          P.out[24576 + row * 3] = Hn; P.out[24576 + row * 3 + 1] = En; P.out[24576 + row * 3 + 2] = Vn;
          P.out[30720 + row * 4] = al; P.out[30720 + row * 4 + 1] = be;
          P.out[30720 + row * 4 + 2] = ga; P.out[30720 + row * 4 + 3] = et;
        }
      }

      // incremental CNN column (lane = channel)
      if (t < 11) {
        float h1a = fast_tanh(b1v + w1v.x * X0 + w1v.y * X1);
        float h1c = fast_tanh(b1v + w1v.x * X2 + w1v.y * xp);
        int src = (lane >> 2) * 4;
        float a2 = b2v;
        a2 += wlo.x * __shfl(h1a, src + 0, 64) + wlo.y * __shfl(h1c, src + 0, 64);
        a2 += wlo.z * __shfl(h1a, src + 1, 64) + wlo.w * __shfl(h1c, src + 1, 64);
        a2 += whi.x * __shfl(h1a, src + 2, 64) + whi.y * __shfl(h1c, src + 2, 64);
        a2 += whi.z * __shfl(h1a, src + 3, 64) + whi.w * __shfl(h1c, src + 3, 64);
        float h2 = fast_tanh(a2);
        float g3 = wsum(w3v * h2);
        float Gn = fast_tanh(P.b3[e] + g3);
        if (lane == 0) {
          GlateS[t * 128 + rowL] = Gn;
          xhS[rowL * 4 + 0] = X1; xhS[rowL * 4 + 1] = X2; xhS[rowL * 4 + 2] = xp;
        }
        gsum_loc += Gn;
      }
    }
    if (t < 11 && lane == 0) atomicAdd(&GsumS[t], gsum_loc);
    __syncthreads();
  }
}

extern "C" void kernel_launch(void* const* d_in, const int* in_sizes, int n_in,
                              void* d_out, int out_size, void* d_ws, size_t ws_size,
                              hipStream_t stream) {
  Params p;
  p.x     = (const float*)d_in[0];  p.noise = (const float*)d_in[1];
  p.aw    = (const float*)d_in[2];  p.ab    = (const float*)d_in[3];
  p.pe_w1 = (const float*)d_in[4];  p.pe_b1 = (const float*)d_in[5];
  p.bn_g  = (const float*)d_in[6];  p.bn_b  = (const float*)d_in[7];
  p.bn_m  = (const float*)d_in[8];  p.bn_v  = (const float*)d_in[9];
  p.pe_w2 = (const float*)d_in[10]; p.pe_b2 = (const float*)d_in[11];
  p.w1    = (const float*)d_in[12]; p.b1    = (const float*)d_in[13];
  p.w2    = (const float*)d_in[14]; p.b2    = (const float*)d_in[15];
  p.w3    = (const float*)d_in[16]; p.b3    = (const float*)d_in[17];
  p.wl    = (const float*)d_in[18]; p.bl    = (const float*)d_in[19];
  p.wr    = (const float*)d_in[20]; p.br    = (const float*)d_in[21];
  p.attn  = (const float*)d_in[22]; p.out_w = (const float*)d_in[23];
  p.out_b = (const float*)d_in[24]; p.ce_w  = (const float*)d_in[25];
  p.ce_b  = (const float*)d_in[26]; p.cd_w  = (const float*)d_in[27];
  p.cd_b  = (const float*)d_in[28]; p.q_w   = (const float*)d_in[29];
  p.q_b   = (const float*)d_in[30]; p.k_w   = (const float*)d_in[31];
  p.k_b   = (const float*)d_in[32];
  p.ws  = (float*)d_ws;
  p.out = (float*)d_out;

  kA   <<<dim3(2048), dim3(256),  0, stream>>>(p);
  kscan<<<dim3(16),   dim3(1024), 0, stream>>>(p);
}